// Round 16
// baseline (2639.585 us; speedup 1.0000x reference)
//
#include <hip/hip_runtime.h>
#include <cstddef>
#include <cstdint>

// LSTM T=512 B=64 D=1024 H=1024.
//   Phase 1: convert x,Wx,Wh -> bf16; xg = x @ Wx^T + bh via MFMA GEMM with
//            global_load_lds(16B) staging + XCD-swizzled grid (~330us).
//            R16: xg stored GATE-PACKED: [t][b][j][4] (one 8B load/lane/step).
//   Phase 2: ONE persistent kernel, 256 blocks x 4 waves (k-split), 512 steps.
//            R9 exchange protocol + R15 pre-poll Wh ds_reads (best: 2098us).
// d_out = [outputs(T,B,H) | h(B,H) | c(B,H)] f32.

#define T_DIM 512
#define B_DIM 64
#define H_DIM 1024
#define G_DIM 4096
#define NBLK 256
#define BAR_STRIDE 16  // ints; one 64B line per flag slot

typedef short short8 __attribute__((ext_vector_type(8)));
typedef float f32x4 __attribute__((ext_vector_type(4)));
typedef unsigned short ushort_t;
typedef unsigned long long u64_t;

__device__ __forceinline__ ushort_t f2b(float f) {   // f32 -> bf16 RNE
  union { float f; unsigned u; } v; v.f = f;
  unsigned r = v.u + 0x7fffu + ((v.u >> 16) & 1u);
  return (ushort_t)(r >> 16);
}
__device__ __forceinline__ float b2f(ushort_t u) {
  union { unsigned u; float f; } v; v.u = ((unsigned)u) << 16;
  return v.f;
}
__device__ __forceinline__ float sigmoidf_(float x) { return 1.0f / (1.0f + __expf(-x)); }

__device__ __forceinline__ void gload_lds16(const ushort_t* g, ushort_t* l) {
  __builtin_amdgcn_global_load_lds(
      (const __attribute__((address_space(1))) unsigned int*)g,
      (__attribute__((address_space(3))) unsigned int*)l, 16, 0, 0);
}

// ---------------------------------------------------------------------------
__global__ __launch_bounds__(256) void reset_flags_kernel(int* __restrict__ flg) {
  int i = blockIdx.x * 256 + threadIdx.x;
  if (i < NBLK * BAR_STRIDE) flg[i] = 0;
}

// convert f32 -> bf16, 8 elems/thread
__global__ __launch_bounds__(256) void convert_bf16_kernel(
    const float* __restrict__ src, ushort_t* __restrict__ dst, int n8) {
  int i = blockIdx.x * 256 + threadIdx.x;
  if (i >= n8) return;
  float4 v0 = *(const float4*)&src[(size_t)i * 8];
  float4 v1 = *(const float4*)&src[(size_t)i * 8 + 4];
  ushort_t p[8] = {f2b(v0.x), f2b(v0.y), f2b(v0.z), f2b(v0.w),
                   f2b(v1.x), f2b(v1.y), f2b(v1.z), f2b(v1.w)};
  *(short8*)&dst[(size_t)i * 8] = *(const short8*)p;
}

// ---------------------------------------------------------------------------
// GEMM: bf16 inputs, global_load_lds(16B) staging, XCD swizzle.
// R16: writes xg gate-packed: C[(m*1024 + j)*4 + g], g = col>>10 (block-
// uniform since 128-wide n-tiles never straddle a 1024-gate boundary).
__global__ __launch_bounds__(256) void xg_gemm_lds(
    const ushort_t* __restrict__ Ab, const ushort_t* __restrict__ Bb,
    const float* __restrict__ bh, ushort_t* __restrict__ C) {
  __shared__ ushort_t As[128 * 64];
  __shared__ ushort_t Bs[128 * 64];
  const int tid = threadIdx.x;
  const int lane = tid & 63;
  const int w = tid >> 6;
  const int wm = w >> 1, wn = w & 1;
  const int flat = (int)blockIdx.x;
  const int swz = (flat & 7) * 1024 + (flat >> 3);
  const size_t m0 = (size_t)(swz & 255) * 128;
  const int n0 = (swz >> 8) * 128;
  const int lr = lane & 15;
  const int lk = (lane >> 4) * 8;
  const int srow = lane >> 3;
  const int schk = lane & 7;

  f32x4 acc[4][4];
#pragma unroll
  for (int i = 0; i < 4; ++i)
#pragma unroll
    for (int j = 0; j < 4; ++j) acc[i][j] = 0.0f;

  for (int k0 = 0; k0 < 1024; k0 += 64) {
    __syncthreads();
#pragma unroll
    for (int i = 0; i < 4; ++i) {
      const int base_row = w * 32 + i * 8;
      const int row = base_row + srow;
      const int csrc = (schk ^ (row & 7)) * 8;
      gload_lds16(&Ab[(m0 + row) * 1024 + k0 + csrc], &As[base_row * 64]);
      gload_lds16(&Bb[(size_t)(n0 + row) * 1024 + k0 + csrc], &Bs[base_row * 64]);
    }
    __syncthreads();
#pragma unroll
    for (int kk = 0; kk < 64; kk += 32) {
      short8 af[4], bf[4];
#pragma unroll
      for (int mf = 0; mf < 4; ++mf) {
        const int row = wm * 64 + mf * 16 + lr;
        const int byte = (row * 128 + (kk + lk) * 2) ^ ((row & 7) << 4);
        af[mf] = *(const short8*)((const char*)As + byte);
      }
#pragma unroll
      for (int nf = 0; nf < 4; ++nf) {
        const int row = wn * 64 + nf * 16 + lr;
        const int byte = (row * 128 + (kk + lk) * 2) ^ ((row & 7) << 4);
        bf[nf] = *(const short8*)((const char*)Bs + byte);
      }
#pragma unroll
      for (int mf = 0; mf < 4; ++mf)
#pragma unroll
        for (int nf = 0; nf < 4; ++nf)
          acc[mf][nf] = __builtin_amdgcn_mfma_f32_16x16x32_bf16(
              af[mf], bf[nf], acc[mf][nf], 0, 0, 0);
    }
  }
#pragma unroll
  for (int nf = 0; nf < 4; ++nf) {
    const int col = n0 + wn * 64 + nf * 16 + lr;
    const int gg = col >> 10;            // gate (block-uniform)
    const int jc = col & 1023;           // j within gate
    const float bias = bh[col];
#pragma unroll
    for (int mf = 0; mf < 4; ++mf) {
      const size_t row0 = m0 + wm * 64 + mf * 16 + (lane >> 4) * 4;
#pragma unroll
      for (int rr = 0; rr < 4; ++rr)
        C[((row0 + rr) * 1024 + jc) * 4 + gg] = f2b(acc[mf][nf][rr] + bias);
    }
  }
}

// ---------------------------------------------------------------------------
// FALLBACK GEMM (f32 inputs reg-staged): used only if ws too small.
// R16: also writes gate-packed xg.
__global__ __launch_bounds__(256) void xg_gemm_mfma(
    const float* __restrict__ A, const float* __restrict__ Bw,
    const float* __restrict__ bh, ushort_t* __restrict__ C) {
  __shared__ ushort_t As[128 * 64];
  __shared__ ushort_t Bs[128 * 64];
  const int tid = threadIdx.x;
  const int lane = tid & 63;
  const int w = tid >> 6;
  const int wm = w >> 1, wn = w & 1;
  const size_t m0 = (size_t)blockIdx.x * 128;
  const int n0 = blockIdx.y * 128;
  const int r = tid >> 1;
  const int kb = (tid & 1) * 32;
  f32x4 acc[4][4];
#pragma unroll
  for (int i = 0; i < 4; ++i)
#pragma unroll
    for (int j = 0; j < 4; ++j) acc[i][j] = 0.0f;
  const int lr = lane & 15;
  const int lk = (lane >> 4) * 8;
  for (int k0 = 0; k0 < 1024; k0 += 64) {
    __syncthreads();
#pragma unroll
    for (int i = 0; i < 4; ++i) {
      const int kk = kb + i * 8;
      float4 a0 = *(const float4*)&A[(m0 + r) * 1024 + k0 + kk];
      float4 a1 = *(const float4*)&A[(m0 + r) * 1024 + k0 + kk + 4];
      ushort_t pa[8] = {f2b(a0.x), f2b(a0.y), f2b(a0.z), f2b(a0.w),
                        f2b(a1.x), f2b(a1.y), f2b(a1.z), f2b(a1.w)};
      float4 b0 = *(const float4*)&Bw[(size_t)(n0 + r) * 1024 + k0 + kk];
      float4 b1 = *(const float4*)&Bw[(size_t)(n0 + r) * 1024 + k0 + kk + 4];
      ushort_t pb[8] = {f2b(b0.x), f2b(b0.y), f2b(b0.z), f2b(b0.w),
                        f2b(b1.x), f2b(b1.y), f2b(b1.z), f2b(b1.w)};
      const int byte = (r * 128 + kk * 2) ^ ((r & 7) << 4);
      *(short8*)((char*)As + byte) = *(const short8*)pa;
      *(short8*)((char*)Bs + byte) = *(const short8*)pb;
    }
    __syncthreads();
#pragma unroll
    for (int kk = 0; kk < 64; kk += 32) {
      short8 af[4], bf[4];
#pragma unroll
      for (int mf = 0; mf < 4; ++mf) {
        const int row = wm * 64 + mf * 16 + lr;
        const int byte = (row * 128 + (kk + lk) * 2) ^ ((row & 7) << 4);
        af[mf] = *(const short8*)((const char*)As + byte);
      }
#pragma unroll
      for (int nf = 0; nf < 4; ++nf) {
        const int row = wn * 64 + nf * 16 + lr;
        const int byte = (row * 128 + (kk + lk) * 2) ^ ((row & 7) << 4);
        bf[nf] = *(const short8*)((const char*)Bs + byte);
      }
#pragma unroll
      for (int mf = 0; mf < 4; ++mf)
#pragma unroll
        for (int nf = 0; nf < 4; ++nf)
          acc[mf][nf] = __builtin_amdgcn_mfma_f32_16x16x32_bf16(
              af[mf], bf[nf], acc[mf][nf], 0, 0, 0);
    }
  }
#pragma unroll
  for (int nf = 0; nf < 4; ++nf) {
    const int col = n0 + wn * 64 + nf * 16 + lr;
    const int gg = col >> 10;
    const int jc = col & 1023;
    const float bias = bh[col];
#pragma unroll
    for (int mf = 0; mf < 4; ++mf) {
      const size_t row0 = m0 + wm * 64 + mf * 16 + (lane >> 4) * 4;
#pragma unroll
      for (int rr = 0; rr < 4; ++rr)
        C[((row0 + rr) * 1024 + jc) * 4 + gg] = f2b(acc[mf][nf][rr] + bias);
    }
  }
}

// ---------------------------------------------------------------------------
// Persistent recurrence, 4-wave k-split, R9 flag protocol + pre-poll ds_reads
// + R16 gate-packed xg (one 8B load per lane per step).
// Block b: j0=(b>>2)*16, w=b&3. Wave v handles ks in [8v, 8v+8).
// Flags: flg[(w*64 + jblk)*BAR_STRIDE] = steps completed by block (jblk,w).
__global__ __launch_bounds__(256) void lstm_persistent(
    const ushort_t* __restrict__ xg,   // [T*64][1024][4] bf16 gate-packed
    const ushort_t* __restrict__ Whb,  // [4096][1024] bf16
    ushort_t* __restrict__ hb0,        // [64][1024] bf16 ping
    ushort_t* __restrict__ hb1,        // [64][1024] bf16 pong
    int* __restrict__ flg,             // [NBLK*BAR_STRIDE] flags (zeroed)
    float* __restrict__ out) {         // [T][64][1024] f32 + tail
  extern __shared__ char smem[];
  ushort_t* Wlds = (ushort_t*)smem;            // 128 KiB, XOR-swizzled
  float* accs = (float*)(smem + 131072);       // 16 KiB reduce buffer
  const int tid = threadIdx.x;
  const int lane = tid & 63;
  const int v = tid >> 6;              // wave id = k-slice
  const int bid = (int)blockIdx.x;
  const int j0 = (bid >> 2) * 16;
  const int w  = bid & 3;
  const int lr = lane & 15;
  const int lq = lane >> 4;            // 0..3

  const int bmine = w * 16 + v * 4 + lq;   // epilogue-owned element
  const int jmine = j0 + lr;
  const int* fpoll = &flg[(w * 64 + lane) * BAR_STRIDE];
  int* fmine = &flg[(w * 64 + (bid >> 2)) * BAR_STRIDE];

  // one-time: stage this block's Wh slice into LDS (swizzled), 256 threads
  for (int e = tid; e < 8192; e += 256) {
    const int r  = e >> 7;
    const int ch = e & 127;
    const int gr = (r >> 4) * 1024 + j0 + (r & 15);
    short8 val = *(const short8*)(Whb + (size_t)gr * 1024 + ch * 8);
    const int byte = (r * 2048 + ch * 16) ^ ((r & 7) << 4);
    *(short8*)((char*)Wlds + byte) = val;
  }
  __syncthreads();

  float creg = 0.f;
  float hv = 0.f;

  for (int t = 0; t < T_DIM; ++t) {
    // prefetch this lane's 4 gate pre-activations: ONE 8B load (gate-packed)
    const u64_t q = *(const u64_t*)&xg[(((size_t)t * 64 + bmine) * 1024 + jmine) * 4];
    float xgv[4];
    xgv[0] = b2f((ushort_t)(q & 0xffffu));
    xgv[1] = b2f((ushort_t)((q >> 16) & 0xffffu));
    xgv[2] = b2f((ushort_t)((q >> 32) & 0xffffu));
    xgv[3] = b2f((ushort_t)(q >> 48));

    f32x4 acc[4];
#pragma unroll
    for (int g = 0; g < 4; ++g) acc[g] = 0.f;

    if (t > 0) {
      // R15: issue the 32 h-independent Wh ds_reads BEFORE the poll; the
      // values sit in VGPRs across the spin (memory clobber pins the order)
      short8 bfr[8][4];
#pragma unroll
      for (int i = 0; i < 8; ++i) {
        const int ksg = v * 8 + i;
#pragma unroll
        for (int g = 0; g < 4; ++g) {
          const int row = g * 16 + lr;
          const int byte = (row * 2048 + ksg * 64 + lq * 16) ^ ((row & 7) << 4);
          bfr[i][g] = *(const short8*)((const char*)Wlds + byte);
        }
      }

      // wave-parallel flag poll: lane L watches producer L of this quarter
      int fv;
      do {
        fv = __hip_atomic_load(fpoll, __ATOMIC_RELAXED,
                               __HIP_MEMORY_SCOPE_AGENT);
      } while (!__all(fv >= t));
      asm volatile("" ::: "memory");   // keep h loads after the poll

      // h loads: wave v covers ks in [8v, 8v+8); k-step = 32 bf16 = 8 u64
      const ushort_t* hprev = (t & 1) ? hb0 : hb1;
      const u64_t* hrow = (const u64_t*)(
          hprev + (size_t)(w * 16 + lr) * 1024 + v * 256 + lq * 8);
      short8 af[8];
#pragma unroll
      for (int i = 0; i < 8; ++i) {
        union { u64_t u[2]; short8 s; } av;
        av.u[0] = __hip_atomic_load(hrow + i * 8, __ATOMIC_RELAXED,
                                    __HIP_MEMORY_SCOPE_AGENT);
        av.u[1] = __hip_atomic_load(hrow + i * 8 + 1, __ATOMIC_RELAXED,
                                    __HIP_MEMORY_SCOPE_AGENT);
        af[i] = av.s;
      }
      // MFMA: pure-register consumers (loads pipeline via vmcnt in order)
#pragma unroll
      for (int i = 0; i < 8; ++i) {
#pragma unroll
        for (int g = 0; g < 4; ++g)
          acc[g] = __builtin_amdgcn_mfma_f32_16x16x32_bf16(af[i], bfr[i][g],
                                                           acc[g], 0, 0, 0);
      }
    }

    // write partials to LDS: [(v*4+g)*64 + lane] * f32x4
#pragma unroll
    for (int g = 0; g < 4; ++g)
      *(f32x4*)&accs[((v * 4 + g) * 64 + lane) * 4] = acc[g];
    __syncthreads();  // sync2

    // epilogue: reduce 4 partials per gate for my (bmine, jmine)
    float gv[4];
#pragma unroll
    for (int g = 0; g < 4; ++g) {
      float s = xgv[g];
#pragma unroll
      for (int v2 = 0; v2 < 4; ++v2)
        s += accs[((v2 * 4 + g) * 64 + v * 16 + lr) * 4 + lq];
      gv[g] = s;
    }
    const float ig = sigmoidf_(gv[0]);
    const float fg = sigmoidf_(gv[1]);
    const float gg = tanhf(gv[2]);
    const float og = sigmoidf_(gv[3]);
    const float cn = fmaf(fg, creg, ig * gg);
    creg = cn;
    hv = og * tanhf(cn);

    // h store (write-through), block-wide drain, publish flag
    ushort_t* hcur = (t & 1) ? hb1 : hb0;
    __hip_atomic_store(&hcur[(size_t)bmine * 1024 + jmine], f2b(hv),
                       __ATOMIC_RELAXED, __HIP_MEMORY_SCOPE_AGENT);
    asm volatile("s_waitcnt vmcnt(0)" ::: "memory");
    __syncthreads();  // sync3: all waves drained + accs WAR

    if (t < T_DIM - 1 && tid == 0)
      __hip_atomic_store(fmine, t + 1, __ATOMIC_RELAXED,
                         __HIP_MEMORY_SCOPE_AGENT);

    // out[] store -- off the inter-block critical path
    out[((size_t)t * 64 + bmine) * 1024 + jmine] = hv;
  }

  // tail: [h_final | c_final]
  const size_t tail = (size_t)T_DIM * B_DIM * H_DIM;
  out[tail + (size_t)bmine * 1024 + jmine] = hv;
  out[tail + (size_t)B_DIM * H_DIM + (size_t)bmine * 1024 + jmine] = creg;
}

// ===========================================================================
extern "C" void kernel_launch(void* const* d_in, const int* in_sizes, int n_in,
                              void* d_out, int out_size, void* d_ws, size_t ws_size,
                              hipStream_t stream) {
  const float* x  = (const float*)d_in[0];
  const float* Wx = (const float*)d_in[1];
  const float* Wh = (const float*)d_in[2];
  const float* bh = (const float*)d_in[3];
  float* out = (float*)d_out;

  const size_t xg_bytes  = (size_t)T_DIM * B_DIM * G_DIM * 2;  // 256 MiB
  const size_t wh_bytes  = (size_t)G_DIM * H_DIM * 2;          // 8 MiB
  const size_t hb_bytes  = (size_t)B_DIM * H_DIM * 2;          // 128 KiB
  const size_t flg_bytes = (size_t)NBLK * BAR_STRIDE * 4;      // 16 KiB
  const size_t x_bytes   = (size_t)T_DIM * B_DIM * H_DIM * 2;  // 64 MiB
  const size_t wx_bytes  = (size_t)G_DIM * H_DIM * 2;          // 8 MiB
  char* ws = (char*)d_ws;

  size_t off = 0;
  ushort_t* xg  = (ushort_t*)(ws + off); off += xg_bytes;
  ushort_t* Whb = (ushort_t*)(ws + off); off += wh_bytes;
  ushort_t* hb0 = (ushort_t*)(ws + off); off += hb_bytes;
  ushort_t* hb1 = (ushort_t*)(ws + off); off += hb_bytes;
  int*      flg = (int*)(ws + off);      off += flg_bytes;
  ushort_t* xb  = (ushort_t*)(ws + off); off += x_bytes;
  ushort_t* wxb = (ushort_t*)(ws + off); off += wx_bytes;
  const size_t need_full = off;

  reset_flags_kernel<<<(NBLK * BAR_STRIDE + 255) / 256, 256, 0, stream>>>(flg);
  convert_bf16_kernel<<<G_DIM * H_DIM / 8 / 256, 256, 0, stream>>>(
      Wh, Whb, G_DIM * H_DIM / 8);

  if (ws_size >= need_full) {
    convert_bf16_kernel<<<T_DIM * B_DIM * H_DIM / 8 / 256, 256, 0, stream>>>(
        x, xb, T_DIM * B_DIM * H_DIM / 8);
    convert_bf16_kernel<<<G_DIM * H_DIM / 8 / 256, 256, 0, stream>>>(
        Wx, wxb, G_DIM * H_DIM / 8);
    xg_gemm_lds<<<8192, 256, 0, stream>>>(xb, wxb, bh, xg);
  } else {
    xg_gemm_mfma<<<dim3(T_DIM * B_DIM / 128, G_DIM / 128), 256, 0, stream>>>(
        x, Wx, bh, xg);
  }
  lstm_persistent<<<NBLK, 256, 147456, stream>>>(xg, Whb, hb0, hb1, flg, out);
}

// Round 17
// 2470.786 us; speedup vs baseline: 1.0683x; 1.0683x over previous
//
#include <hip/hip_runtime.h>
#include <cstddef>
#include <cstdint>

// LSTM T=512 B=64 D=1024 H=1024.  FINAL (= round-15 best: 2473 us total).
//   Phase 1: convert x,Wx,Wh -> bf16; xg = x @ Wx^T + bh via MFMA GEMM with
//            global_load_lds(16B) staging + XCD-swizzled grid (~330us).
//   Phase 2: ONE persistent kernel, 256 blocks x 4 waves (k-split), 512 steps.
//            R9 exchange protocol: write-through bf16 h stores + L2-bypassing
//            agent loads + per-producer block flags (wave-parallel 4B poll);
//            R15: the 32 h-independent Wh ds_read_b128s issued BEFORE the
//            poll (VGPR-resident across the spin).
//   Per-step cost ~4.1us = ~3 agent-scope L3 RTs (publish->detect, h-load,
//   store-drain) + compute/barriers: latency-floor, not a pipe roofline
//   (MfmaUtil 5%, HBM 3%). R11/R12/R13/R14/R16 variants all regressed or null.
// d_out = [outputs(T,B,H) | h(B,H) | c(B,H)] f32.

#define T_DIM 512
#define B_DIM 64
#define H_DIM 1024
#define G_DIM 4096
#define NBLK 256
#define BAR_STRIDE 16  // ints; one 64B line per flag slot

typedef short short8 __attribute__((ext_vector_type(8)));
typedef float f32x4 __attribute__((ext_vector_type(4)));
typedef unsigned short ushort_t;
typedef unsigned long long u64_t;

__device__ __forceinline__ ushort_t f2b(float f) {   // f32 -> bf16 RNE
  union { float f; unsigned u; } v; v.f = f;
  unsigned r = v.u + 0x7fffu + ((v.u >> 16) & 1u);
  return (ushort_t)(r >> 16);
}
__device__ __forceinline__ float b2f(ushort_t u) {
  union { unsigned u; float f; } v; v.u = ((unsigned)u) << 16;
  return v.f;
}
__device__ __forceinline__ float sigmoidf_(float x) { return 1.0f / (1.0f + __expf(-x)); }

__device__ __forceinline__ void gload_lds16(const ushort_t* g, ushort_t* l) {
  __builtin_amdgcn_global_load_lds(
      (const __attribute__((address_space(1))) unsigned int*)g,
      (__attribute__((address_space(3))) unsigned int*)l, 16, 0, 0);
}

// ---------------------------------------------------------------------------
__global__ __launch_bounds__(256) void reset_flags_kernel(int* __restrict__ flg) {
  int i = blockIdx.x * 256 + threadIdx.x;
  if (i < NBLK * BAR_STRIDE) flg[i] = 0;
}

// convert f32 -> bf16, 8 elems/thread
__global__ __launch_bounds__(256) void convert_bf16_kernel(
    const float* __restrict__ src, ushort_t* __restrict__ dst, int n8) {
  int i = blockIdx.x * 256 + threadIdx.x;
  if (i >= n8) return;
  float4 v0 = *(const float4*)&src[(size_t)i * 8];
  float4 v1 = *(const float4*)&src[(size_t)i * 8 + 4];
  ushort_t p[8] = {f2b(v0.x), f2b(v0.y), f2b(v0.z), f2b(v0.w),
                   f2b(v1.x), f2b(v1.y), f2b(v1.z), f2b(v1.w)};
  *(short8*)&dst[(size_t)i * 8] = *(const short8*)p;
}

// ---------------------------------------------------------------------------
// GEMM: bf16 inputs, global_load_lds(16B) staging, XCD swizzle. (round-9)
__global__ __launch_bounds__(256) void xg_gemm_lds(
    const ushort_t* __restrict__ Ab, const ushort_t* __restrict__ Bb,
    const float* __restrict__ bh, ushort_t* __restrict__ C) {
  __shared__ ushort_t As[128 * 64];
  __shared__ ushort_t Bs[128 * 64];
  const int tid = threadIdx.x;
  const int lane = tid & 63;
  const int w = tid >> 6;
  const int wm = w >> 1, wn = w & 1;
  const int flat = (int)blockIdx.x;
  const int swz = (flat & 7) * 1024 + (flat >> 3);
  const size_t m0 = (size_t)(swz & 255) * 128;
  const int n0 = (swz >> 8) * 128;
  const int lr = lane & 15;
  const int lk = (lane >> 4) * 8;
  const int srow = lane >> 3;
  const int schk = lane & 7;

  f32x4 acc[4][4];
#pragma unroll
  for (int i = 0; i < 4; ++i)
#pragma unroll
    for (int j = 0; j < 4; ++j) acc[i][j] = 0.0f;

  for (int k0 = 0; k0 < 1024; k0 += 64) {
    __syncthreads();
#pragma unroll
    for (int i = 0; i < 4; ++i) {
      const int base_row = w * 32 + i * 8;
      const int row = base_row + srow;
      const int csrc = (schk ^ (row & 7)) * 8;
      gload_lds16(&Ab[(m0 + row) * 1024 + k0 + csrc], &As[base_row * 64]);
      gload_lds16(&Bb[(size_t)(n0 + row) * 1024 + k0 + csrc], &Bs[base_row * 64]);
    }
    __syncthreads();
#pragma unroll
    for (int kk = 0; kk < 64; kk += 32) {
      short8 af[4], bf[4];
#pragma unroll
      for (int mf = 0; mf < 4; ++mf) {
        const int row = wm * 64 + mf * 16 + lr;
        const int byte = (row * 128 + (kk + lk) * 2) ^ ((row & 7) << 4);
        af[mf] = *(const short8*)((const char*)As + byte);
      }
#pragma unroll
      for (int nf = 0; nf < 4; ++nf) {
        const int row = wn * 64 + nf * 16 + lr;
        const int byte = (row * 128 + (kk + lk) * 2) ^ ((row & 7) << 4);
        bf[nf] = *(const short8*)((const char*)Bs + byte);
      }
#pragma unroll
      for (int mf = 0; mf < 4; ++mf)
#pragma unroll
        for (int nf = 0; nf < 4; ++nf)
          acc[mf][nf] = __builtin_amdgcn_mfma_f32_16x16x32_bf16(
              af[mf], bf[nf], acc[mf][nf], 0, 0, 0);
    }
  }
#pragma unroll
  for (int nf = 0; nf < 4; ++nf) {
    const int col = n0 + wn * 64 + nf * 16 + lr;
    const float bias = bh[col];
#pragma unroll
    for (int mf = 0; mf < 4; ++mf) {
      const size_t row0 = m0 + wm * 64 + mf * 16 + (lane >> 4) * 4;
#pragma unroll
      for (int rr = 0; rr < 4; ++rr)
        C[(row0 + rr) * 4096 + col] = f2b(acc[mf][nf][rr] + bias);
    }
  }
}

// ---------------------------------------------------------------------------
// FALLBACK GEMM (f32 inputs reg-staged): used only if ws too small.
__global__ __launch_bounds__(256) void xg_gemm_mfma(
    const float* __restrict__ A, const float* __restrict__ Bw,
    const float* __restrict__ bh, ushort_t* __restrict__ C) {
  __shared__ ushort_t As[128 * 64];
  __shared__ ushort_t Bs[128 * 64];
  const int tid = threadIdx.x;
  const int lane = tid & 63;
  const int w = tid >> 6;
  const int wm = w >> 1, wn = w & 1;
  const size_t m0 = (size_t)blockIdx.x * 128;
  const int n0 = blockIdx.y * 128;
  const int r = tid >> 1;
  const int kb = (tid & 1) * 32;
  f32x4 acc[4][4];
#pragma unroll
  for (int i = 0; i < 4; ++i)
#pragma unroll
    for (int j = 0; j < 4; ++j) acc[i][j] = 0.0f;
  const int lr = lane & 15;
  const int lk = (lane >> 4) * 8;
  for (int k0 = 0; k0 < 1024; k0 += 64) {
    __syncthreads();
#pragma unroll
    for (int i = 0; i < 4; ++i) {
      const int kk = kb + i * 8;
      float4 a0 = *(const float4*)&A[(m0 + r) * 1024 + k0 + kk];
      float4 a1 = *(const float4*)&A[(m0 + r) * 1024 + k0 + kk + 4];
      ushort_t pa[8] = {f2b(a0.x), f2b(a0.y), f2b(a0.z), f2b(a0.w),
                        f2b(a1.x), f2b(a1.y), f2b(a1.z), f2b(a1.w)};
      float4 b0 = *(const float4*)&Bw[(size_t)(n0 + r) * 1024 + k0 + kk];
      float4 b1 = *(const float4*)&Bw[(size_t)(n0 + r) * 1024 + k0 + kk + 4];
      ushort_t pb[8] = {f2b(b0.x), f2b(b0.y), f2b(b0.z), f2b(b0.w),
                        f2b(b1.x), f2b(b1.y), f2b(b1.z), f2b(b1.w)};
      const int byte = (r * 128 + kk * 2) ^ ((r & 7) << 4);
      *(short8*)((char*)As + byte) = *(const short8*)pa;
      *(short8*)((char*)Bs + byte) = *(const short8*)pb;
    }
    __syncthreads();
#pragma unroll
    for (int kk = 0; kk < 64; kk += 32) {
      short8 af[4], bf[4];
#pragma unroll
      for (int mf = 0; mf < 4; ++mf) {
        const int row = wm * 64 + mf * 16 + lr;
        const int byte = (row * 128 + (kk + lk) * 2) ^ ((row & 7) << 4);
        af[mf] = *(const short8*)((const char*)As + byte);
      }
#pragma unroll
      for (int nf = 0; nf < 4; ++nf) {
        const int row = wn * 64 + nf * 16 + lr;
        const int byte = (row * 128 + (kk + lk) * 2) ^ ((row & 7) << 4);
        bf[nf] = *(const short8*)((const char*)Bs + byte);
      }
#pragma unroll
      for (int mf = 0; mf < 4; ++mf)
#pragma unroll
        for (int nf = 0; nf < 4; ++nf)
          acc[mf][nf] = __builtin_amdgcn_mfma_f32_16x16x32_bf16(
              af[mf], bf[nf], acc[mf][nf], 0, 0, 0);
    }
  }
#pragma unroll
  for (int nf = 0; nf < 4; ++nf) {
    const int col = n0 + wn * 64 + nf * 16 + lr;
    const float bias = bh[col];
#pragma unroll
    for (int mf = 0; mf < 4; ++mf) {
      const size_t row0 = m0 + wm * 64 + mf * 16 + (lane >> 4) * 4;
#pragma unroll
      for (int rr = 0; rr < 4; ++rr)
        C[(row0 + rr) * 4096 + col] = f2b(acc[mf][nf][rr] + bias);
    }
  }
}

// ---------------------------------------------------------------------------
// Persistent recurrence, 4-wave k-split, R9 flag protocol + pre-poll ds_reads.
// Block b: j0=(b>>2)*16, w=b&3. Wave v handles ks in [8v, 8v+8).
// Flags: flg[(w*64 + jblk)*BAR_STRIDE] = steps completed by block (jblk,w).
__global__ __launch_bounds__(256) void lstm_persistent(
    const ushort_t* __restrict__ xg,   // [T*64][4096] bf16 (bias folded)
    const ushort_t* __restrict__ Whb,  // [4096][1024] bf16
    ushort_t* __restrict__ hb0,        // [64][1024] bf16 ping
    ushort_t* __restrict__ hb1,        // [64][1024] bf16 pong
    int* __restrict__ flg,             // [NBLK*BAR_STRIDE] flags (zeroed)
    float* __restrict__ out) {         // [T][64][1024] f32 + tail
  extern __shared__ char smem[];
  ushort_t* Wlds = (ushort_t*)smem;            // 128 KiB, XOR-swizzled
  float* accs = (float*)(smem + 131072);       // 16 KiB reduce buffer
  const int tid = threadIdx.x;
  const int lane = tid & 63;
  const int v = tid >> 6;              // wave id = k-slice
  const int bid = (int)blockIdx.x;
  const int j0 = (bid >> 2) * 16;
  const int w  = bid & 3;
  const int lr = lane & 15;
  const int lq = lane >> 4;            // 0..3

  const int bmine = w * 16 + v * 4 + lq;   // epilogue-owned element
  const int jmine = j0 + lr;
  const int* fpoll = &flg[(w * 64 + lane) * BAR_STRIDE];
  int* fmine = &flg[(w * 64 + (bid >> 2)) * BAR_STRIDE];

  // one-time: stage this block's Wh slice into LDS (swizzled), 256 threads
  for (int e = tid; e < 8192; e += 256) {
    const int r  = e >> 7;
    const int ch = e & 127;
    const int gr = (r >> 4) * 1024 + j0 + (r & 15);
    short8 val = *(const short8*)(Whb + (size_t)gr * 1024 + ch * 8);
    const int byte = (r * 2048 + ch * 16) ^ ((r & 7) << 4);
    *(short8*)((char*)Wlds + byte) = val;
  }
  __syncthreads();

  float creg = 0.f;
  float hv = 0.f;

  for (int t = 0; t < T_DIM; ++t) {
    // prefetch this lane's xg (independent of h) before the poll
    const size_t xbase = ((size_t)t * 64 + bmine) * 4096 + jmine;
    float xgv[4];
#pragma unroll
    for (int g = 0; g < 4; ++g) xgv[g] = b2f(xg[xbase + (size_t)g * 1024]);

    f32x4 acc[4];
#pragma unroll
    for (int g = 0; g < 4; ++g) acc[g] = 0.f;

    if (t > 0) {
      // R15: issue the 32 h-independent Wh ds_reads BEFORE the poll; the
      // values sit in VGPRs across the spin (memory clobber pins the order)
      short8 bfr[8][4];
#pragma unroll
      for (int i = 0; i < 8; ++i) {
        const int ksg = v * 8 + i;
#pragma unroll
        for (int g = 0; g < 4; ++g) {
          const int row = g * 16 + lr;
          const int byte = (row * 2048 + ksg * 64 + lq * 16) ^ ((row & 7) << 4);
          bfr[i][g] = *(const short8*)((const char*)Wlds + byte);
        }
      }

      // wave-parallel flag poll: lane L watches producer L of this quarter
      int fv;
      do {
        fv = __hip_atomic_load(fpoll, __ATOMIC_RELAXED,
                               __HIP_MEMORY_SCOPE_AGENT);
      } while (!__all(fv >= t));
      asm volatile("" ::: "memory");   // keep h loads after the poll

      // h loads: wave v covers ks in [8v, 8v+8); k-step = 32 bf16 = 8 u64
      const ushort_t* hprev = (t & 1) ? hb0 : hb1;
      const u64_t* hrow = (const u64_t*)(
          hprev + (size_t)(w * 16 + lr) * 1024 + v * 256 + lq * 8);
      short8 af[8];
#pragma unroll
      for (int i = 0; i < 8; ++i) {
        union { u64_t u[2]; short8 s; } av;
        av.u[0] = __hip_atomic_load(hrow + i * 8, __ATOMIC_RELAXED,
                                    __HIP_MEMORY_SCOPE_AGENT);
        av.u[1] = __hip_atomic_load(hrow + i * 8 + 1, __ATOMIC_RELAXED,
                                    __HIP_MEMORY_SCOPE_AGENT);
        af[i] = av.s;
      }
      // MFMA: pure-register consumers (loads pipeline via vmcnt in order)
#pragma unroll
      for (int i = 0; i < 8; ++i) {
#pragma unroll
        for (int g = 0; g < 4; ++g)
          acc[g] = __builtin_amdgcn_mfma_f32_16x16x32_bf16(af[i], bfr[i][g],
                                                           acc[g], 0, 0, 0);
      }
    }

    // write partials to LDS: [(v*4+g)*64 + lane] * f32x4
#pragma unroll
    for (int g = 0; g < 4; ++g)
      *(f32x4*)&accs[((v * 4 + g) * 64 + lane) * 4] = acc[g];
    __syncthreads();  // sync2

    // epilogue: reduce 4 partials per gate for my (bmine, jmine)
    float gv[4];
#pragma unroll
    for (int g = 0; g < 4; ++g) {
      float s = xgv[g];
#pragma unroll
      for (int v2 = 0; v2 < 4; ++v2)
        s += accs[((v2 * 4 + g) * 64 + v * 16 + lr) * 4 + lq];
      gv[g] = s;
    }
    const float ig = sigmoidf_(gv[0]);
    const float fg = sigmoidf_(gv[1]);
    const float gg = tanhf(gv[2]);
    const float og = sigmoidf_(gv[3]);
    const float cn = fmaf(fg, creg, ig * gg);
    creg = cn;
    hv = og * tanhf(cn);

    // h store (write-through), block-wide drain, publish flag
    ushort_t* hcur = (t & 1) ? hb1 : hb0;
    __hip_atomic_store(&hcur[(size_t)bmine * 1024 + jmine], f2b(hv),
                       __ATOMIC_RELAXED, __HIP_MEMORY_SCOPE_AGENT);
    asm volatile("s_waitcnt vmcnt(0)" ::: "memory");
    __syncthreads();  // sync3: all waves drained + accs WAR

    if (t < T_DIM - 1 && tid == 0)
      __hip_atomic_store(fmine, t + 1, __ATOMIC_RELAXED,
                         __HIP_MEMORY_SCOPE_AGENT);

    // out[] store -- off the inter-block critical path
    out[((size_t)t * 64 + bmine) * 1024 + jmine] = hv;
  }

  // tail: [h_final | c_final]
  const size_t tail = (size_t)T_DIM * B_DIM * H_DIM;
  out[tail + (size_t)bmine * 1024 + jmine] = hv;
  out[tail + (size_t)B_DIM * H_DIM + (size_t)bmine * 1024 + jmine] = creg;
}

// ===========================================================================
extern "C" void kernel_launch(void* const* d_in, const int* in_sizes, int n_in,
                              void* d_out, int out_size, void* d_ws, size_t ws_size,
                              hipStream_t stream) {
  const float* x  = (const float*)d_in[0];
  const float* Wx = (const float*)d_in[1];
  const float* Wh = (const float*)d_in[2];
  const float* bh = (const float*)d_in[3];
  float* out = (float*)d_out;

  const size_t xg_bytes  = (size_t)T_DIM * B_DIM * G_DIM * 2;  // 256 MiB
  const size_t wh_bytes  = (size_t)G_DIM * H_DIM * 2;          // 8 MiB
  const size_t hb_bytes  = (size_t)B_DIM * H_DIM * 2;          // 128 KiB
  const size_t flg_bytes = (size_t)NBLK * BAR_STRIDE * 4;      // 16 KiB
  const size_t x_bytes   = (size_t)T_DIM * B_DIM * H_DIM * 2;  // 64 MiB
  const size_t wx_bytes  = (size_t)G_DIM * H_DIM * 2;          // 8 MiB
  char* ws = (char*)d_ws;

  size_t off = 0;
  ushort_t* xg  = (ushort_t*)(ws + off); off += xg_bytes;
  ushort_t* Whb = (ushort_t*)(ws + off); off += wh_bytes;
  ushort_t* hb0 = (ushort_t*)(ws + off); off += hb_bytes;
  ushort_t* hb1 = (ushort_t*)(ws + off); off += hb_bytes;
  int*      flg = (int*)(ws + off);      off += flg_bytes;
  ushort_t* xb  = (ushort_t*)(ws + off); off += x_bytes;
  ushort_t* wxb = (ushort_t*)(ws + off); off += wx_bytes;
  const size_t need_full = off;

  reset_flags_kernel<<<(NBLK * BAR_STRIDE + 255) / 256, 256, 0, stream>>>(flg);
  convert_bf16_kernel<<<G_DIM * H_DIM / 8 / 256, 256, 0, stream>>>(
      Wh, Whb, G_DIM * H_DIM / 8);

  if (ws_size >= need_full) {
    convert_bf16_kernel<<<T_DIM * B_DIM * H_DIM / 8 / 256, 256, 0, stream>>>(
        x, xb, T_DIM * B_DIM * H_DIM / 8);
    convert_bf16_kernel<<<G_DIM * H_DIM / 8 / 256, 256, 0, stream>>>(
        Wx, wxb, G_DIM * H_DIM / 8);
    xg_gemm_lds<<<8192, 256, 0, stream>>>(xb, wxb, bh, xg);
  } else {
    xg_gemm_mfma<<<dim3(T_DIM * B_DIM / 128, G_DIM / 128), 256, 0, stream>>>(
        x, Wx, bh, xg);
  }
  lstm_persistent<<<NBLK, 256, 147456, stream>>>(xg, Whb, hb0, hb1, flg, out);
}